// Round 4
// baseline (1434.127 us; speedup 1.0000x reference)
//
#include <hip/hip_runtime.h>
#include <stdint.h>

// ---------------- types ----------------
typedef short bf16x8 __attribute__((ext_vector_type(8)));
typedef float f32x16 __attribute__((ext_vector_type(16)));
typedef float f32x4  __attribute__((ext_vector_type(4)));
typedef float f32x2  __attribute__((ext_vector_type(2)));

#define NODES  2
#define LAYERS 4
#define HD     256
#define MTILE  256                // rows per block = 4 waves x 64 rows
#define QBYTES 32768              // one K-quarter of one layer: 256 n x 64 k x 2B
#define NQ     (NODES*LAYERS*4)   // 32 staged quarters

__device__ __forceinline__ unsigned short f2bf(float f) {  // RNE f32->bf16
  unsigned u = __float_as_uint(f);
  u += 0x7fffu + ((u >> 16) & 1u);
  return (unsigned short)(u >> 16);
}
__device__ __forceinline__ float bf2f(unsigned short s) {
  return __uint_as_float(((unsigned)s) << 16);
}
__device__ __forceinline__ float elu1(float v) {
  return v > 0.0f ? v : (__expf(v) - 1.0f);
}
__device__ __forceinline__ unsigned cvtpk(float lo, float hi) {  // low16=bf16(lo)
  unsigned r;
  asm("v_cvt_pk_bf16_f32 %0, %1, %2" : "=v"(r) : "v"(lo), "v"(hi));
  return r;
}
union U8 { bf16x8 v; unsigned u[4]; };

#define GLOAD_LDS16(gsrc, ldst)                                                        \
  __builtin_amdgcn_global_load_lds(                                                    \
      (const __attribute__((address_space(1))) unsigned int*)(gsrc),                   \
      (__attribute__((address_space(3))) unsigned int*)(ldst), 16, 0, 0)

// Blob layout (unchanged from round 3, conflict-free, zero-swizzle):
// per (node,layer) 4 quarters of 32KB; quarter = [kc(4)][g(2)][nf(8)][l31(32)]x16B.
// Fragment element i holds k = 64*qq + 16*kc + 4*g + (i&3) + 8*(i>>2)
// (sigma permutation: D-frags feed next layer's B operand with no cross-lane ops).
__global__ __launch_bounds__(256) void convw_kernel(const float* __restrict__ w_hid,
                                                    unsigned short* __restrict__ blob) {
  int e = blockIdx.x * 256 + threadIdx.x;    // 0 .. 2*4*256*256-1
  int nl = e >> 16;                          // node*4+layer
  int k  = (e >> 8) & 255;
  int n  = e & 255;
  float v = w_hid[(nl * 256 + k) * 256 + n];
  int qq  = k >> 6;
  int kc  = (k >> 4) & 3;
  int k16 = k & 15;
  int g   = (k16 >> 2) & 1;
  int i   = (k16 & 3) | ((k16 >> 3) << 2);
  int nf  = n >> 5, l31 = n & 31;
  unsigned boff = ((unsigned)(nl * 4 + qq) << 15)
                + ((unsigned)kc << 13) + ((unsigned)g << 12)
                + ((unsigned)nf << 9) + ((unsigned)l31 << 4) + ((unsigned)i << 1);
  blob[boff >> 1] = f2bf(v);
}

// ---------------- main fused kernel ----------------
// 4 waves x 64 rows (two 32-row MFMA groups per wave). Each W fragment feeds
// 2 MFMAs -> LDS read volume halved. Ring-3 staging + counted vmcnt(8) + raw
// s_barrier: no full waitcnt drain in the main loop.
__global__ __launch_bounds__(256, 1) void nld_kernel(
    const float* __restrict__ uv, const float* __restrict__ w_in,
    const float* __restrict__ b_in, const float* __restrict__ b_hid,
    const float* __restrict__ w_out, const float* __restrict__ b_out,
    const unsigned short* __restrict__ blob, float* __restrict__ out, int nrows) {

  __shared__ __attribute__((aligned(16))) char  w_sm[3 * QBYTES];            // 96KB ring
  __shared__ __attribute__((aligned(16))) float pb_hid[NODES * LAYERS * HD]; // 8KB
  __shared__ __attribute__((aligned(16))) float pb_in[NODES * HD];           // 2KB

  const int t    = threadIdx.x;
  const int lane = t & 63;
  const int wv   = t >> 6;        // 0..3
  const int l31  = lane & 31;
  const int g    = lane >> 5;
  const long row0 = (long)blockIdx.x * MTILE + wv * 64 + l31;
  const long row1 = row0 + 32;

  auto stage = [&](int iq, unsigned dsto) {   // one 32KB quarter -> w_sm[dsto..]
    const char* src = (const char*)blob + (size_t)iq * QBYTES + t * 16;
    char* dst = &w_sm[dsto + t * 16];
#pragma unroll
    for (int r = 0; r < 8; ++r) GLOAD_LDS16(src + r * 4096, dst + r * 4096);
  };

  stage(0, 0);
  stage(1, QBYTES);
  for (int i = t; i < NODES * LAYERS * HD; i += 256) pb_hid[i] = b_hid[i];
  for (int i = t; i < NODES * HD; i += 256) pb_in[i] = b_in[i];

  float x00 = 0.f, x01 = 0.f, x10 = 0.f, x11 = 0.f;
  if (row0 < nrows) { f32x2 u = *(const f32x2*)(uv + row0 * 2); x00 = u[0]; x01 = u[1]; }
  if (row1 < nrows) { f32x2 u = *(const f32x2*)(uv + row1 * 2); x10 = u[0]; x11 = u[1]; }
  __syncthreads();   // params + prologue staging ordering (full drain once)

  bf16x8 hb0[16], hb1[16];
  const unsigned fbase = (unsigned)(g * 4096 + l31 * 16);
  unsigned ro = 0, no = QBYTES, fo = 2 * QBYTES;   // ring offsets: read/next/free

  for (int nd = 0; nd < NODES; ++nd) {
    // ---- input layer: both rows share weight registers
    {
      const float* wi0 = w_in + nd * 2 * HD;
      const float* wi1 = wi0 + HD;
      const float* bi  = &pb_in[nd * HD];
#pragma unroll
      for (int c = 0; c < 16; ++c) {
        int kb = 16 * c + 4 * g;
        f32x4 a0 = *(const f32x4*)(wi0 + kb);
        f32x4 a1 = *(const f32x4*)(wi0 + kb + 8);
        f32x4 c0 = *(const f32x4*)(wi1 + kb);
        f32x4 c1 = *(const f32x4*)(wi1 + kb + 8);
        f32x4 e0 = *(const f32x4*)(bi + kb);
        f32x4 e1 = *(const f32x4*)(bi + kb + 8);
        float p0[8], p1[8];
#pragma unroll
        for (int j = 0; j < 4; ++j) {
          p0[j]     = elu1(fmaf(x01, c0[j], fmaf(x00, a0[j], e0[j])));
          p0[4 + j] = elu1(fmaf(x01, c1[j], fmaf(x00, a1[j], e1[j])));
          p1[j]     = elu1(fmaf(x11, c0[j], fmaf(x10, a0[j], e0[j])));
          p1[4 + j] = elu1(fmaf(x11, c1[j], fmaf(x10, a1[j], e1[j])));
        }
        U8 q0, q1;
        q0.u[0] = cvtpk(p0[0], p0[1]); q0.u[1] = cvtpk(p0[2], p0[3]);
        q0.u[2] = cvtpk(p0[4], p0[5]); q0.u[3] = cvtpk(p0[6], p0[7]);
        q1.u[0] = cvtpk(p1[0], p1[1]); q1.u[1] = cvtpk(p1[2], p1[3]);
        q1.u[2] = cvtpk(p1[4], p1[5]); q1.u[3] = cvtpk(p1[6], p1[7]);
        hb0[c] = q0.v;
        hb1[c] = q1.v;
      }
    }

    // ---- 4 hidden layers
    for (int ly = 0; ly < LAYERS; ++ly) {
      const float* bl = &pb_hid[(nd * LAYERS + ly) * HD];
      f32x16 acc0[8], acc1[8];
#pragma unroll
      for (int nf = 0; nf < 8; ++nf) {     // acc init = bias (same for both groups)
        int nb = 32 * nf + 4 * g;
        f32x4 b0 = *(const f32x4*)(bl + nb);
        f32x4 b1 = *(const f32x4*)(bl + nb + 8);
        f32x4 b2 = *(const f32x4*)(bl + nb + 16);
        f32x4 b3 = *(const f32x4*)(bl + nb + 24);
#pragma unroll
        for (int j = 0; j < 4; ++j) {
          acc0[nf][j]      = b0[j]; acc1[nf][j]      = b0[j];
          acc0[nf][4 + j]  = b1[j]; acc1[nf][4 + j]  = b1[j];
          acc0[nf][8 + j]  = b2[j]; acc1[nf][8 + j]  = b2[j];
          acc0[nf][12 + j] = b3[j]; acc1[nf][12 + j] = b3[j];
        }
      }

      const int iq0 = (nd * LAYERS + ly) * 4;
#pragma unroll
      for (int qq = 0; qq < 4; ++qq) {
        int iq = iq0 + qq;
        // T4: my stage(iq) done when <=8 newer loads outstanding; barrier makes
        // it true for all waves. Full drain only on the very last quarter.
        if (iq == NQ - 1) asm volatile("s_waitcnt vmcnt(0)" ::: "memory");
        else              asm volatile("s_waitcnt vmcnt(8)" ::: "memory");
        __builtin_amdgcn_s_barrier();
        if (iq + 2 < NQ) stage(iq + 2, fo);
        const char* wb = &w_sm[ro + fbase];
        __builtin_amdgcn_s_setprio(1);
#pragma unroll
        for (int kc = 0; kc < 4; ++kc) {
          bf16x8 wf0 = *(const bf16x8*)(wb + kc * 8192 + 0 * 512);
          bf16x8 wf1 = *(const bf16x8*)(wb + kc * 8192 + 1 * 512);
          bf16x8 wf2 = *(const bf16x8*)(wb + kc * 8192 + 2 * 512);
          bf16x8 wf3 = *(const bf16x8*)(wb + kc * 8192 + 3 * 512);
          bf16x8 wf4 = *(const bf16x8*)(wb + kc * 8192 + 4 * 512);
          bf16x8 wf5 = *(const bf16x8*)(wb + kc * 8192 + 5 * 512);
          bf16x8 wf6 = *(const bf16x8*)(wb + kc * 8192 + 6 * 512);
          bf16x8 wf7 = *(const bf16x8*)(wb + kc * 8192 + 7 * 512);
          bf16x8 h0 = hb0[4 * qq + kc], h1 = hb1[4 * qq + kc];
          acc0[0] = __builtin_amdgcn_mfma_f32_32x32x16_bf16(wf0, h0, acc0[0], 0, 0, 0);
          acc1[0] = __builtin_amdgcn_mfma_f32_32x32x16_bf16(wf0, h1, acc1[0], 0, 0, 0);
          acc0[1] = __builtin_amdgcn_mfma_f32_32x32x16_bf16(wf1, h0, acc0[1], 0, 0, 0);
          acc1[1] = __builtin_amdgcn_mfma_f32_32x32x16_bf16(wf1, h1, acc1[1], 0, 0, 0);
          acc0[2] = __builtin_amdgcn_mfma_f32_32x32x16_bf16(wf2, h0, acc0[2], 0, 0, 0);
          acc1[2] = __builtin_amdgcn_mfma_f32_32x32x16_bf16(wf2, h1, acc1[2], 0, 0, 0);
          acc0[3] = __builtin_amdgcn_mfma_f32_32x32x16_bf16(wf3, h0, acc0[3], 0, 0, 0);
          acc1[3] = __builtin_amdgcn_mfma_f32_32x32x16_bf16(wf3, h1, acc1[3], 0, 0, 0);
          acc0[4] = __builtin_amdgcn_mfma_f32_32x32x16_bf16(wf4, h0, acc0[4], 0, 0, 0);
          acc1[4] = __builtin_amdgcn_mfma_f32_32x32x16_bf16(wf4, h1, acc1[4], 0, 0, 0);
          acc0[5] = __builtin_amdgcn_mfma_f32_32x32x16_bf16(wf5, h0, acc0[5], 0, 0, 0);
          acc1[5] = __builtin_amdgcn_mfma_f32_32x32x16_bf16(wf5, h1, acc1[5], 0, 0, 0);
          acc0[6] = __builtin_amdgcn_mfma_f32_32x32x16_bf16(wf6, h0, acc0[6], 0, 0, 0);
          acc1[6] = __builtin_amdgcn_mfma_f32_32x32x16_bf16(wf6, h1, acc1[6], 0, 0, 0);
          acc0[7] = __builtin_amdgcn_mfma_f32_32x32x16_bf16(wf7, h0, acc0[7], 0, 0, 0);
          acc1[7] = __builtin_amdgcn_mfma_f32_32x32x16_bf16(wf7, h1, acc1[7], 0, 0, 0);
        }
        __builtin_amdgcn_s_setprio(0);
        unsigned tmp = ro; ro = no; no = fo; fo = tmp;   // rotate ring
      }

      // ---- transform: acc -> hb (ELU + cvt_pk), both groups
#pragma unroll
      for (int nf = 0; nf < 8; ++nf) {
        float e0[16], e1[16];
#pragma unroll
        for (int j = 0; j < 16; ++j) { e0[j] = elu1(acc0[nf][j]); e1[j] = elu1(acc1[nf][j]); }
        U8 p, q, r, s;
        p.u[0] = cvtpk(e0[0],  e0[1]);  p.u[1] = cvtpk(e0[2],  e0[3]);
        p.u[2] = cvtpk(e0[4],  e0[5]);  p.u[3] = cvtpk(e0[6],  e0[7]);
        q.u[0] = cvtpk(e0[8],  e0[9]);  q.u[1] = cvtpk(e0[10], e0[11]);
        q.u[2] = cvtpk(e0[12], e0[13]); q.u[3] = cvtpk(e0[14], e0[15]);
        r.u[0] = cvtpk(e1[0],  e1[1]);  r.u[1] = cvtpk(e1[2],  e1[3]);
        r.u[2] = cvtpk(e1[4],  e1[5]);  r.u[3] = cvtpk(e1[6],  e1[7]);
        s.u[0] = cvtpk(e1[8],  e1[9]);  s.u[1] = cvtpk(e1[10], e1[11]);
        s.u[2] = cvtpk(e1[12], e1[13]); s.u[3] = cvtpk(e1[14], e1[15]);
        hb0[2 * nf] = p.v; hb0[2 * nf + 1] = q.v;
        hb1[2 * nf] = r.v; hb1[2 * nf + 1] = s.v;
      }
    }

    // ---- output layer: x += h @ w_out + b_out, both rows share weight regs
    {
      const float* wo = w_out + nd * HD * 2;
      float s00 = 0.f, s01 = 0.f, s10 = 0.f, s11 = 0.f;
#pragma unroll
      for (int c = 0; c < 16; ++c) {
        int kb = 16 * c + 4 * g;
        f32x4 wA0 = *(const f32x4*)(wo + kb * 2);
        f32x4 wA1 = *(const f32x4*)(wo + kb * 2 + 4);
        f32x4 wB0 = *(const f32x4*)(wo + (kb + 8) * 2);
        f32x4 wB1 = *(const f32x4*)(wo + (kb + 8) * 2 + 4);
        bf16x8 h0 = hb0[c], h1 = hb1[c];
#pragma unroll
        for (int j = 0; j < 2; ++j) {
          float f0 = bf2f((unsigned short)h0[2 * j]),     g0 = bf2f((unsigned short)h1[2 * j]);
          float f1 = bf2f((unsigned short)h0[2 * j + 1]), g1 = bf2f((unsigned short)h1[2 * j + 1]);
          float f2 = bf2f((unsigned short)h0[2 * j + 4]), g2 = bf2f((unsigned short)h1[2 * j + 4]);
          float f3 = bf2f((unsigned short)h0[2 * j + 5]), g3 = bf2f((unsigned short)h1[2 * j + 5]);
          const f32x4& wa = j ? wA1 : wA0;
          const f32x4& wbv = j ? wB1 : wB0;
          s00 = fmaf(f0, wa[0], s00);  s01 = fmaf(f0, wa[1], s01);
          s10 = fmaf(g0, wa[0], s10);  s11 = fmaf(g0, wa[1], s11);
          s00 = fmaf(f1, wa[2], s00);  s01 = fmaf(f1, wa[3], s01);
          s10 = fmaf(g1, wa[2], s10);  s11 = fmaf(g1, wa[3], s11);
          s00 = fmaf(f2, wbv[0], s00); s01 = fmaf(f2, wbv[1], s01);
          s10 = fmaf(g2, wbv[0], s10); s11 = fmaf(g2, wbv[1], s11);
          s00 = fmaf(f3, wbv[2], s00); s01 = fmaf(f3, wbv[3], s01);
          s10 = fmaf(g3, wbv[2], s10); s11 = fmaf(g3, wbv[3], s11);
        }
      }
      s00 += __shfl_xor(s00, 32); s01 += __shfl_xor(s01, 32);
      s10 += __shfl_xor(s10, 32); s11 += __shfl_xor(s11, 32);
      float bo0 = b_out[nd * 2 + 0], bo1 = b_out[nd * 2 + 1];
      x00 += s00 + bo0; x01 += s01 + bo1;
      x10 += s10 + bo0; x11 += s11 + bo1;
    }
  }

  if (g == 0) {
    if (row0 < nrows) { f32x2 r; r[0] = x00; r[1] = x01; *(f32x2*)(out + row0 * 2) = r; }
    if (row1 < nrows) { f32x2 r; r[0] = x10; r[1] = x11; *(f32x2*)(out + row1 * 2) = r; }
  }
}

// ---------------- launcher ----------------
extern "C" void kernel_launch(void* const* d_in, const int* in_sizes, int n_in,
                              void* d_out, int out_size, void* d_ws, size_t ws_size,
                              hipStream_t stream) {
  const float* uv    = (const float*)d_in[0];
  const float* w_in  = (const float*)d_in[1];
  const float* b_in  = (const float*)d_in[2];
  const float* w_hid = (const float*)d_in[3];
  const float* b_hid = (const float*)d_in[4];
  const float* w_out = (const float*)d_in[5];
  const float* b_out = (const float*)d_in[6];
  unsigned short* blob = (unsigned short*)d_ws;   // 1 MB bf16 permuted blob

  int whid_elems = in_sizes[3];                   // 524288
  convw_kernel<<<whid_elems / 256, 256, 0, stream>>>(w_hid, blob);

  int N = in_sizes[0] / 2;                        // 1048576 rows
  int grid = (N + MTILE - 1) / MTILE;             // 4096
  nld_kernel<<<grid, 256, 0, stream>>>(uv, w_in, b_in, b_hid, w_out, b_out,
                                       blob, (float*)d_out, N);
}

// Round 5
// 1266.163 us; speedup vs baseline: 1.1327x; 1.1327x over previous
//
#include <hip/hip_runtime.h>
#include <stdint.h>

// ---------------- types ----------------
typedef short bf16x8 __attribute__((ext_vector_type(8)));
typedef float f32x16 __attribute__((ext_vector_type(16)));
typedef float f32x4  __attribute__((ext_vector_type(4)));
typedef float f32x2  __attribute__((ext_vector_type(2)));

#define NODES  2
#define LAYERS 4
#define HD     256
#define MTILE  256                // rows per block = 4 waves x 64 rows
#define GRPB   8192               // bytes per kc-group in blob (16k x 256n bf16)
#define NGRP   (NODES*LAYERS*16)  // 128 groups total

__device__ __forceinline__ unsigned short f2bf(float f) {  // RNE f32->bf16
  unsigned u = __float_as_uint(f);
  u += 0x7fffu + ((u >> 16) & 1u);
  return (unsigned short)(u >> 16);
}
__device__ __forceinline__ float bf2f(unsigned short s) {
  return __uint_as_float(((unsigned)s) << 16);
}
__device__ __forceinline__ float elu1(float v) {
  return v > 0.0f ? v : (__expf(v) - 1.0f);
}
__device__ __forceinline__ unsigned cvtpk(float lo, float hi) {  // low16=bf16(lo)
  unsigned r;
  asm("v_cvt_pk_bf16_f32 %0, %1, %2" : "=v"(r) : "v"(lo), "v"(hi));
  return r;
}
union U8 { bf16x8 v; unsigned u[4]; };

// Blob layout (unchanged semantics from rounds 3/4):
// group gi = ((node*4+layer)*4 + qq)*4 + kc, 8KB each: [g(2)][nf(8)][l31(32)]x16B.
// Fragment element i holds k = 64*qq + 16*kc + 4*g + (i&3) + 8*(i>>2)
// (sigma permutation: D-frags feed next layer's B operand with no cross-lane ops).
__global__ __launch_bounds__(256) void convw_kernel(const float* __restrict__ w_hid,
                                                    unsigned short* __restrict__ blob) {
  int e = blockIdx.x * 256 + threadIdx.x;    // 0 .. 2*4*256*256-1
  int nl = e >> 16;                          // node*4+layer
  int k  = (e >> 8) & 255;
  int n  = e & 255;
  float v = w_hid[(nl * 256 + k) * 256 + n];
  int qq  = k >> 6;
  int kc  = (k >> 4) & 3;
  int k16 = k & 15;
  int g   = (k16 >> 2) & 1;
  int i   = (k16 & 3) | ((k16 >> 3) << 2);
  int nf  = n >> 5, l31 = n & 31;
  unsigned boff = ((unsigned)(nl * 4 + qq) << 15)
                + ((unsigned)kc << 13) + ((unsigned)g << 12)
                + ((unsigned)nf << 9) + ((unsigned)l31 << 4) + ((unsigned)i << 1);
  blob[boff >> 1] = f2bf(v);
}

// half-group: 4 W fragments (nf j..j+3), 16 VGPRs
struct HG { bf16x8 a, b, c, d; };

__device__ __forceinline__ HG load_hg(const char* __restrict__ p) {
  HG r;
  r.a = *(const bf16x8*)(p);
  r.b = *(const bf16x8*)(p + 512);
  r.c = *(const bf16x8*)(p + 1024);
  r.d = *(const bf16x8*)(p + 1536);
  return r;
}

#define MM(af, h, accv) accv = __builtin_amdgcn_mfma_f32_32x32x16_bf16(af, h, accv, 0, 0, 0)

// ---------------- main fused kernel ----------------
// 4 waves x 64 rows, NO LDS staging, NO barriers (except one init sync).
// W streams L1/L2 -> registers, double-buffered at half-group granularity.
__global__ __launch_bounds__(256, 1) void nld_kernel(
    const float* __restrict__ uv, const float* __restrict__ w_in,
    const float* __restrict__ b_in, const float* __restrict__ b_hid,
    const float* __restrict__ w_out, const float* __restrict__ b_out,
    const unsigned short* __restrict__ blob, float* __restrict__ out, int nrows) {

  __shared__ __attribute__((aligned(16))) float pb_hid[NODES * LAYERS * HD]; // 8KB
  __shared__ __attribute__((aligned(16))) float pb_in[NODES * HD];           // 2KB

  const int t    = threadIdx.x;
  const int lane = t & 63;
  const int wv   = t >> 6;        // 0..3
  const int l31  = lane & 31;
  const int g    = lane >> 5;
  const long row0 = (long)blockIdx.x * MTILE + wv * 64 + l31;
  const long row1 = row0 + 32;

  for (int i = t; i < NODES * LAYERS * HD; i += 256) pb_hid[i] = b_hid[i];
  for (int i = t; i < NODES * HD; i += 256) pb_in[i] = b_in[i];

  float x00 = 0.f, x01 = 0.f, x10 = 0.f, x11 = 0.f;
  if (row0 < nrows) { f32x2 u = *(const f32x2*)(uv + row0 * 2); x00 = u[0]; x01 = u[1]; }
  if (row1 < nrows) { f32x2 u = *(const f32x2*)(uv + row1 * 2); x10 = u[0]; x11 = u[1]; }
  __syncthreads();   // params visible (only barrier in the kernel)

  bf16x8 hb0[16], hb1[16];
  const unsigned voff = (unsigned)(g * 4096 + l31 * 16);  // per-lane offset in group
  const char* gp   = (const char*)blob;                   // current group (uniform)
  const char* gend = (const char*)blob + (size_t)(NGRP - 1) * GRPB;

  HG A = load_hg(gp + voff);     // preload group 0, half 0 (in flight during input)

  for (int nd = 0; nd < NODES; ++nd) {
    // ---- input layer: both rows share weight registers
    {
      const float* wi0 = w_in + nd * 2 * HD;
      const float* wi1 = wi0 + HD;
      const float* bi  = &pb_in[nd * HD];
#pragma unroll
      for (int c = 0; c < 16; ++c) {
        int kb = 16 * c + 4 * g;
        f32x4 a0 = *(const f32x4*)(wi0 + kb);
        f32x4 a1 = *(const f32x4*)(wi0 + kb + 8);
        f32x4 c0 = *(const f32x4*)(wi1 + kb);
        f32x4 c1 = *(const f32x4*)(wi1 + kb + 8);
        f32x4 e0 = *(const f32x4*)(bi + kb);
        f32x4 e1 = *(const f32x4*)(bi + kb + 8);
        float p0[8], p1[8];
#pragma unroll
        for (int j = 0; j < 4; ++j) {
          p0[j]     = elu1(fmaf(x01, c0[j], fmaf(x00, a0[j], e0[j])));
          p0[4 + j] = elu1(fmaf(x01, c1[j], fmaf(x00, a1[j], e1[j])));
          p1[j]     = elu1(fmaf(x11, c0[j], fmaf(x10, a0[j], e0[j])));
          p1[4 + j] = elu1(fmaf(x11, c1[j], fmaf(x10, a1[j], e1[j])));
        }
        U8 q0, q1;
        q0.u[0] = cvtpk(p0[0], p0[1]); q0.u[1] = cvtpk(p0[2], p0[3]);
        q0.u[2] = cvtpk(p0[4], p0[5]); q0.u[3] = cvtpk(p0[6], p0[7]);
        q1.u[0] = cvtpk(p1[0], p1[1]); q1.u[1] = cvtpk(p1[2], p1[3]);
        q1.u[2] = cvtpk(p1[4], p1[5]); q1.u[3] = cvtpk(p1[6], p1[7]);
        hb0[c] = q0.v;
        hb1[c] = q1.v;
      }
    }

    // ---- 4 hidden layers
    for (int ly = 0; ly < LAYERS; ++ly) {
      const float* bl = &pb_hid[(nd * LAYERS + ly) * HD];
      f32x16 acc0[8], acc1[8];
#pragma unroll
      for (int nf = 0; nf < 8; ++nf) {     // acc init = bias (same for both groups)
        int nb = 32 * nf + 4 * g;
        f32x4 b0 = *(const f32x4*)(bl + nb);
        f32x4 b1 = *(const f32x4*)(bl + nb + 8);
        f32x4 b2 = *(const f32x4*)(bl + nb + 16);
        f32x4 b3 = *(const f32x4*)(bl + nb + 24);
#pragma unroll
        for (int j = 0; j < 4; ++j) {
          acc0[nf][j]      = b0[j]; acc1[nf][j]      = b0[j];
          acc0[nf][4 + j]  = b1[j]; acc1[nf][4 + j]  = b1[j];
          acc0[nf][8 + j]  = b2[j]; acc1[nf][8 + j]  = b2[j];
          acc0[nf][12 + j] = b3[j]; acc1[nf][12 + j] = b3[j];
        }
      }

      // 16 kc-groups; A holds half0 of current group at loop entry.
      // Each half-group's 4 loads are covered by the other half's 8 MFMAs.
#pragma unroll
      for (int u = 0; u < 16; ++u) {
        HG B = load_hg(gp + voff + 2048);          // half1 (nf 4..7) of group u
        bf16x8 h0 = hb0[u], h1 = hb1[u];
        MM(A.a, h0, acc0[0]); MM(A.a, h1, acc1[0]);
        MM(A.b, h0, acc0[1]); MM(A.b, h1, acc1[1]);
        MM(A.c, h0, acc0[2]); MM(A.c, h1, acc1[2]);
        MM(A.d, h0, acc0[3]); MM(A.d, h1, acc1[3]);
        const char* nx = gp + GRPB;                // next group (crosses layers/nodes)
        if (nx > gend) nx = gend;                  // final-group clamp (dead load)
        A = load_hg(nx + voff);                    // half0 of next group
        MM(B.a, h0, acc0[4]); MM(B.a, h1, acc1[4]);
        MM(B.b, h0, acc0[5]); MM(B.b, h1, acc1[5]);
        MM(B.c, h0, acc0[6]); MM(B.c, h1, acc1[6]);
        MM(B.d, h0, acc0[7]); MM(B.d, h1, acc1[7]);
        gp = nx;
      }

      // ---- transform: acc -> hb (ELU + cvt_pk), both groups (bias already in)
#pragma unroll
      for (int nf = 0; nf < 8; ++nf) {
        float e0[16], e1[16];
#pragma unroll
        for (int j = 0; j < 16; ++j) { e0[j] = elu1(acc0[nf][j]); e1[j] = elu1(acc1[nf][j]); }
        U8 p, q, r, s;
        p.u[0] = cvtpk(e0[0],  e0[1]);  p.u[1] = cvtpk(e0[2],  e0[3]);
        p.u[2] = cvtpk(e0[4],  e0[5]);  p.u[3] = cvtpk(e0[6],  e0[7]);
        q.u[0] = cvtpk(e0[8],  e0[9]);  q.u[1] = cvtpk(e0[10], e0[11]);
        q.u[2] = cvtpk(e0[12], e0[13]); q.u[3] = cvtpk(e0[14], e0[15]);
        r.u[0] = cvtpk(e1[0],  e1[1]);  r.u[1] = cvtpk(e1[2],  e1[3]);
        r.u[2] = cvtpk(e1[4],  e1[5]);  r.u[3] = cvtpk(e1[6],  e1[7]);
        s.u[0] = cvtpk(e1[8],  e1[9]);  s.u[1] = cvtpk(e1[10], e1[11]);
        s.u[2] = cvtpk(e1[12], e1[13]); s.u[3] = cvtpk(e1[14], e1[15]);
        hb0[2 * nf] = p.v; hb0[2 * nf + 1] = q.v;
        hb1[2 * nf] = r.v; hb1[2 * nf + 1] = s.v;
      }
    }

    // ---- output layer: x += h @ w_out + b_out, both rows share weight regs
    {
      const float* wo = w_out + nd * HD * 2;
      float s00 = 0.f, s01 = 0.f, s10 = 0.f, s11 = 0.f;
#pragma unroll
      for (int c = 0; c < 16; ++c) {
        int kb = 16 * c + 4 * g;
        f32x4 wA0 = *(const f32x4*)(wo + kb * 2);
        f32x4 wA1 = *(const f32x4*)(wo + kb * 2 + 4);
        f32x4 wB0 = *(const f32x4*)(wo + (kb + 8) * 2);
        f32x4 wB1 = *(const f32x4*)(wo + (kb + 8) * 2 + 4);
        bf16x8 h0 = hb0[c], h1 = hb1[c];
#pragma unroll
        for (int j = 0; j < 2; ++j) {
          float f0 = bf2f((unsigned short)h0[2 * j]),     g0 = bf2f((unsigned short)h1[2 * j]);
          float f1 = bf2f((unsigned short)h0[2 * j + 1]), g1 = bf2f((unsigned short)h1[2 * j + 1]);
          float f2 = bf2f((unsigned short)h0[2 * j + 4]), g2 = bf2f((unsigned short)h1[2 * j + 4]);
          float f3 = bf2f((unsigned short)h0[2 * j + 5]), g3 = bf2f((unsigned short)h1[2 * j + 5]);
          const f32x4& wa = j ? wA1 : wA0;
          const f32x4& wbv = j ? wB1 : wB0;
          s00 = fmaf(f0, wa[0], s00);  s01 = fmaf(f0, wa[1], s01);
          s10 = fmaf(g0, wa[0], s10);  s11 = fmaf(g0, wa[1], s11);
          s00 = fmaf(f1, wa[2], s00);  s01 = fmaf(f1, wa[3], s01);
          s10 = fmaf(g1, wa[2], s10);  s11 = fmaf(g1, wa[3], s11);
          s00 = fmaf(f2, wbv[0], s00); s01 = fmaf(f2, wbv[1], s01);
          s10 = fmaf(g2, wbv[0], s10); s11 = fmaf(g2, wbv[1], s11);
          s00 = fmaf(f3, wbv[2], s00); s01 = fmaf(f3, wbv[3], s01);
          s10 = fmaf(g3, wbv[2], s10); s11 = fmaf(g3, wbv[3], s11);
        }
      }
      s00 += __shfl_xor(s00, 32); s01 += __shfl_xor(s01, 32);
      s10 += __shfl_xor(s10, 32); s11 += __shfl_xor(s11, 32);
      float bo0 = b_out[nd * 2 + 0], bo1 = b_out[nd * 2 + 1];
      x00 += s00 + bo0; x01 += s01 + bo1;
      x10 += s10 + bo0; x11 += s11 + bo1;
    }
  }

  if (g == 0) {
    if (row0 < nrows) { f32x2 r; r[0] = x00; r[1] = x01; *(f32x2*)(out + row0 * 2) = r; }
    if (row1 < nrows) { f32x2 r; r[0] = x10; r[1] = x11; *(f32x2*)(out + row1 * 2) = r; }
  }
}

// ---------------- launcher ----------------
extern "C" void kernel_launch(void* const* d_in, const int* in_sizes, int n_in,
                              void* d_out, int out_size, void* d_ws, size_t ws_size,
                              hipStream_t stream) {
  const float* uv    = (const float*)d_in[0];
  const float* w_in  = (const float*)d_in[1];
  const float* b_in  = (const float*)d_in[2];
  const float* w_hid = (const float*)d_in[3];
  const float* b_hid = (const float*)d_in[4];
  const float* w_out = (const float*)d_in[5];
  const float* b_out = (const float*)d_in[6];
  unsigned short* blob = (unsigned short*)d_ws;   // 1 MB bf16 permuted blob

  int whid_elems = in_sizes[3];                   // 524288
  convw_kernel<<<whid_elems / 256, 256, 0, stream>>>(w_hid, blob);

  int N = in_sizes[0] / 2;                        // 1048576 rows
  int grid = (N + MTILE - 1) / MTILE;             // 4096
  nld_kernel<<<grid, 256, 0, stream>>>(uv, w_in, b_in, b_hid, w_out, b_out,
                                       blob, (float*)d_out, N);
}

// Round 6
// 1249.959 us; speedup vs baseline: 1.1473x; 1.0130x over previous
//
#include <hip/hip_runtime.h>
#include <stdint.h>

// ---------------- types ----------------
typedef short bf16x8 __attribute__((ext_vector_type(8)));
typedef float f32x16 __attribute__((ext_vector_type(16)));
typedef float f32x4  __attribute__((ext_vector_type(4)));
typedef float f32x2  __attribute__((ext_vector_type(2)));

#define NODES  2
#define LAYERS 4
#define HD     256
#define MTILE  256                // rows per block = 4 waves x 64 rows
#define GRPB   8192               // bytes per kc-group in blob (16k x 256n bf16)
#define NGRP   (NODES*LAYERS*16)  // 128 groups total

__device__ __forceinline__ unsigned short f2bf(float f) {  // RNE f32->bf16
  unsigned u = __float_as_uint(f);
  u += 0x7fffu + ((u >> 16) & 1u);
  return (unsigned short)(u >> 16);
}
__device__ __forceinline__ float bf2f(unsigned short s) {
  return __uint_as_float(((unsigned)s) << 16);
}
__device__ __forceinline__ float elu1(float v) {
  return v > 0.0f ? v : (__expf(v) - 1.0f);
}
__device__ __forceinline__ unsigned cvtpk(float lo, float hi) {  // low16=bf16(lo)
  unsigned r;
  asm("v_cvt_pk_bf16_f32 %0, %1, %2" : "=v"(r) : "v"(lo), "v"(hi));
  return r;
}
union U8 { bf16x8 v; unsigned u[4]; };

// Blob layout (unchanged semantics from rounds 3-5):
// group gi = ((node*4+layer)*4 + qq)*4 + kc, 8KB each: [g(2)][nf(8)][l31(32)]x16B.
// Fragment element i holds k = 64*qq + 16*kc + 4*g + (i&3) + 8*(i>>2)
// (sigma permutation: D-frags feed next layer's B operand with no cross-lane ops).
__global__ __launch_bounds__(256) void convw_kernel(const float* __restrict__ w_hid,
                                                    unsigned short* __restrict__ blob) {
  int e = blockIdx.x * 256 + threadIdx.x;    // 0 .. 2*4*256*256-1
  int nl = e >> 16;                          // node*4+layer
  int k  = (e >> 8) & 255;
  int n  = e & 255;
  float v = w_hid[(nl * 256 + k) * 256 + n];
  int qq  = k >> 6;
  int kc  = (k >> 4) & 3;
  int k16 = k & 15;
  int g   = (k16 >> 2) & 1;
  int i   = (k16 & 3) | ((k16 >> 3) << 2);
  int nf  = n >> 5, l31 = n & 31;
  unsigned boff = ((unsigned)(nl * 4 + qq) << 15)
                + ((unsigned)kc << 13) + ((unsigned)g << 12)
                + ((unsigned)nf << 9) + ((unsigned)l31 << 4) + ((unsigned)i << 1);
  blob[boff >> 1] = f2bf(v);
}

// half-group: 4 W fragments (nf j..j+3), 16 VGPRs
struct HG { bf16x8 a, b, c, d; };

__device__ __forceinline__ HG load_hg(const char* __restrict__ p) {
  HG r;
  r.a = *(const bf16x8*)(p);
  r.b = *(const bf16x8*)(p + 512);
  r.c = *(const bf16x8*)(p + 1024);
  r.d = *(const bf16x8*)(p + 1536);
  return r;
}

#define MM(af, h, accv) accv = __builtin_amdgcn_mfma_f32_32x32x16_bf16(af, h, accv, 0, 0, 0)

// ---------------- main fused kernel ----------------
// 4 waves x 64 rows, NO LDS staging, NO barriers (except one init sync).
// W streams L1/L2 -> registers. Parity double-buffer (A0/B0/A1/B1): iteration
// u consumes parity u&1 and refills it for group u+2 right after last use ->
// prefetch distance = 2 full iterations (~256+ cyc) > L2 hit latency.
__global__ __launch_bounds__(256, 1) void nld_kernel(
    const float* __restrict__ uv, const float* __restrict__ w_in,
    const float* __restrict__ b_in, const float* __restrict__ b_hid,
    const float* __restrict__ w_out, const float* __restrict__ b_out,
    const unsigned short* __restrict__ blob, float* __restrict__ out, int nrows) {

  __shared__ __attribute__((aligned(16))) float pb_hid[NODES * LAYERS * HD]; // 8KB
  __shared__ __attribute__((aligned(16))) float pb_in[NODES * HD];           // 2KB

  const int t    = threadIdx.x;
  const int lane = t & 63;
  const int wv   = t >> 6;        // 0..3
  const int l31  = lane & 31;
  const int g    = lane >> 5;
  const long row0 = (long)blockIdx.x * MTILE + wv * 64 + l31;
  const long row1 = row0 + 32;

  bf16x8 hb0[16], hb1[16];
  const unsigned voff = (unsigned)(g * 4096 + l31 * 16);  // per-lane offset in group
  const char* gend = (const char*)blob + (size_t)(NGRP - 1) * GRPB;

  // preload groups 0 (parity 0) and 1 (parity 1); in flight during param/input setup
  HG A0 = load_hg((const char*)blob + voff);
  HG B0 = load_hg((const char*)blob + voff + 2048);
  HG A1 = load_hg((const char*)blob + GRPB + voff);
  HG B1 = load_hg((const char*)blob + GRPB + voff + 2048);
  const char* rp = (const char*)blob + 2 * GRPB;   // next group to refill (uniform)

  for (int i = t; i < NODES * LAYERS * HD; i += 256) pb_hid[i] = b_hid[i];
  for (int i = t; i < NODES * HD; i += 256) pb_in[i] = b_in[i];

  float x00 = 0.f, x01 = 0.f, x10 = 0.f, x11 = 0.f;
  if (row0 < nrows) { f32x2 u = *(const f32x2*)(uv + row0 * 2); x00 = u[0]; x01 = u[1]; }
  if (row1 < nrows) { f32x2 u = *(const f32x2*)(uv + row1 * 2); x10 = u[0]; x11 = u[1]; }
  __syncthreads();   // params visible (only barrier in the kernel)

  for (int nd = 0; nd < NODES; ++nd) {
    // ---- input layer: both rows share weight registers
    {
      const float* wi0 = w_in + nd * 2 * HD;
      const float* wi1 = wi0 + HD;
      const float* bi  = &pb_in[nd * HD];
#pragma unroll
      for (int c = 0; c < 16; ++c) {
        int kb = 16 * c + 4 * g;
        f32x4 a0 = *(const f32x4*)(wi0 + kb);
        f32x4 a1 = *(const f32x4*)(wi0 + kb + 8);
        f32x4 c0 = *(const f32x4*)(wi1 + kb);
        f32x4 c1 = *(const f32x4*)(wi1 + kb + 8);
        f32x4 e0 = *(const f32x4*)(bi + kb);
        f32x4 e1 = *(const f32x4*)(bi + kb + 8);
        float p0[8], p1[8];
#pragma unroll
        for (int j = 0; j < 4; ++j) {
          p0[j]     = elu1(fmaf(x01, c0[j], fmaf(x00, a0[j], e0[j])));
          p0[4 + j] = elu1(fmaf(x01, c1[j], fmaf(x00, a1[j], e1[j])));
          p1[j]     = elu1(fmaf(x11, c0[j], fmaf(x10, a0[j], e0[j])));
          p1[4 + j] = elu1(fmaf(x11, c1[j], fmaf(x10, a1[j], e1[j])));
        }
        U8 q0, q1;
        q0.u[0] = cvtpk(p0[0], p0[1]); q0.u[1] = cvtpk(p0[2], p0[3]);
        q0.u[2] = cvtpk(p0[4], p0[5]); q0.u[3] = cvtpk(p0[6], p0[7]);
        q1.u[0] = cvtpk(p1[0], p1[1]); q1.u[1] = cvtpk(p1[2], p1[3]);
        q1.u[2] = cvtpk(p1[4], p1[5]); q1.u[3] = cvtpk(p1[6], p1[7]);
        hb0[c] = q0.v;
        hb1[c] = q1.v;
      }
    }

    // ---- 4 hidden layers
    for (int ly = 0; ly < LAYERS; ++ly) {
      const float* bl = &pb_hid[(nd * LAYERS + ly) * HD];
      f32x16 acc0[8], acc1[8];
#pragma unroll
      for (int nf = 0; nf < 8; ++nf) {     // acc init = bias (same for both groups)
        int nb = 32 * nf + 4 * g;
        f32x4 b0 = *(const f32x4*)(bl + nb);
        f32x4 b1 = *(const f32x4*)(bl + nb + 8);
        f32x4 b2 = *(const f32x4*)(bl + nb + 16);
        f32x4 b3 = *(const f32x4*)(bl + nb + 24);
#pragma unroll
        for (int j = 0; j < 4; ++j) {
          acc0[nf][j]      = b0[j]; acc1[nf][j]      = b0[j];
          acc0[nf][4 + j]  = b1[j]; acc1[nf][4 + j]  = b1[j];
          acc0[nf][8 + j]  = b2[j]; acc1[nf][8 + j]  = b2[j];
          acc0[nf][12 + j] = b3[j]; acc1[nf][12 + j] = b3[j];
        }
      }

      // 16 kc-groups, parity double-buffered, refilled at distance 2.
#pragma unroll
      for (int u = 0; u < 16; ++u) {
        bf16x8 h0 = hb0[u], h1 = hb1[u];
        if ((u & 1) == 0) {
          MM(A0.a, h0, acc0[0]); MM(A0.a, h1, acc1[0]);
          MM(A0.b, h0, acc0[1]); MM(A0.b, h1, acc1[1]);
          MM(A0.c, h0, acc0[2]); MM(A0.c, h1, acc1[2]);
          MM(A0.d, h0, acc0[3]); MM(A0.d, h1, acc1[3]);
          A0 = load_hg(rp + voff);                 // refill for group u+2
          MM(B0.a, h0, acc0[4]); MM(B0.a, h1, acc1[4]);
          MM(B0.b, h0, acc0[5]); MM(B0.b, h1, acc1[5]);
          MM(B0.c, h0, acc0[6]); MM(B0.c, h1, acc1[6]);
          MM(B0.d, h0, acc0[7]); MM(B0.d, h1, acc1[7]);
          B0 = load_hg(rp + voff + 2048);
        } else {
          MM(A1.a, h0, acc0[0]); MM(A1.a, h1, acc1[0]);
          MM(A1.b, h0, acc0[1]); MM(A1.b, h1, acc1[1]);
          MM(A1.c, h0, acc0[2]); MM(A1.c, h1, acc1[2]);
          MM(A1.d, h0, acc0[3]); MM(A1.d, h1, acc1[3]);
          A1 = load_hg(rp + voff);
          MM(B1.a, h0, acc0[4]); MM(B1.a, h1, acc1[4]);
          MM(B1.b, h0, acc0[5]); MM(B1.b, h1, acc1[5]);
          MM(B1.c, h0, acc0[6]); MM(B1.c, h1, acc1[6]);
          MM(B1.d, h0, acc0[7]); MM(B1.d, h1, acc1[7]);
          B1 = load_hg(rp + voff + 2048);
        }
        const char* nx = rp + GRPB;                // advance refill ptr, clamp at end
        rp = (nx > gend) ? gend : nx;
      }

      // ---- transform: acc -> hb (ELU + cvt_pk), both groups (bias already in)
#pragma unroll
      for (int nf = 0; nf < 8; ++nf) {
        float e0[16], e1[16];
#pragma unroll
        for (int j = 0; j < 16; ++j) { e0[j] = elu1(acc0[nf][j]); e1[j] = elu1(acc1[nf][j]); }
        U8 p, q, r, s;
        p.u[0] = cvtpk(e0[0],  e0[1]);  p.u[1] = cvtpk(e0[2],  e0[3]);
        p.u[2] = cvtpk(e0[4],  e0[5]);  p.u[3] = cvtpk(e0[6],  e0[7]);
        q.u[0] = cvtpk(e0[8],  e0[9]);  q.u[1] = cvtpk(e0[10], e0[11]);
        q.u[2] = cvtpk(e0[12], e0[13]); q.u[3] = cvtpk(e0[14], e0[15]);
        r.u[0] = cvtpk(e1[0],  e1[1]);  r.u[1] = cvtpk(e1[2],  e1[3]);
        r.u[2] = cvtpk(e1[4],  e1[5]);  r.u[3] = cvtpk(e1[6],  e1[7]);
        s.u[0] = cvtpk(e1[8],  e1[9]);  s.u[1] = cvtpk(e1[10], e1[11]);
        s.u[2] = cvtpk(e1[12], e1[13]); s.u[3] = cvtpk(e1[14], e1[15]);
        hb0[2 * nf] = p.v; hb0[2 * nf + 1] = q.v;
        hb1[2 * nf] = r.v; hb1[2 * nf + 1] = s.v;
      }
    }

    // ---- output layer: x += h @ w_out + b_out, both rows share weight regs
    {
      const float* wo = w_out + nd * HD * 2;
      float s00 = 0.f, s01 = 0.f, s10 = 0.f, s11 = 0.f;
#pragma unroll
      for (int c = 0; c < 16; ++c) {
        int kb = 16 * c + 4 * g;
        f32x4 wA0 = *(const f32x4*)(wo + kb * 2);
        f32x4 wA1 = *(const f32x4*)(wo + kb * 2 + 4);
        f32x4 wB0 = *(const f32x4*)(wo + (kb + 8) * 2);
        f32x4 wB1 = *(const f32x4*)(wo + (kb + 8) * 2 + 4);
        bf16x8 h0 = hb0[c], h1 = hb1[c];
#pragma unroll
        for (int j = 0; j < 2; ++j) {
          float f0 = bf2f((unsigned short)h0[2 * j]),     g0 = bf2f((unsigned short)h1[2 * j]);
          float f1 = bf2f((unsigned short)h0[2 * j + 1]), g1 = bf2f((unsigned short)h1[2 * j + 1]);
          float f2 = bf2f((unsigned short)h0[2 * j + 4]), g2 = bf2f((unsigned short)h1[2 * j + 4]);
          float f3 = bf2f((unsigned short)h0[2 * j + 5]), g3 = bf2f((unsigned short)h1[2 * j + 5]);
          const f32x4& wa = j ? wA1 : wA0;
          const f32x4& wbv = j ? wB1 : wB0;
          s00 = fmaf(f0, wa[0], s00);  s01 = fmaf(f0, wa[1], s01);
          s10 = fmaf(g0, wa[0], s10);  s11 = fmaf(g0, wa[1], s11);
          s00 = fmaf(f1, wa[2], s00);  s01 = fmaf(f1, wa[3], s01);
          s10 = fmaf(g1, wa[2], s10);  s11 = fmaf(g1, wa[3], s11);
          s00 = fmaf(f2, wbv[0], s00); s01 = fmaf(f2, wbv[1], s01);
          s10 = fmaf(g2, wbv[0], s10); s11 = fmaf(g2, wbv[1], s11);
          s00 = fmaf(f3, wbv[2], s00); s01 = fmaf(f3, wbv[3], s01);
          s10 = fmaf(g3, wbv[2], s10); s11 = fmaf(g3, wbv[3], s11);
        }
      }
      s00 += __shfl_xor(s00, 32); s01 += __shfl_xor(s01, 32);
      s10 += __shfl_xor(s10, 32); s11 += __shfl_xor(s11, 32);
      float bo0 = b_out[nd * 2 + 0], bo1 = b_out[nd * 2 + 1];
      x00 += s00 + bo0; x01 += s01 + bo1;
      x10 += s10 + bo0; x11 += s11 + bo1;
    }
  }

  if (g == 0) {
    if (row0 < nrows) { f32x2 r; r[0] = x00; r[1] = x01; *(f32x2*)(out + row0 * 2) = r; }
    if (row1 < nrows) { f32x2 r; r[0] = x10; r[1] = x11; *(f32x2*)(out + row1 * 2) = r; }
  }
}

// ---------------- launcher ----------------
extern "C" void kernel_launch(void* const* d_in, const int* in_sizes, int n_in,
                              void* d_out, int out_size, void* d_ws, size_t ws_size,
                              hipStream_t stream) {
  const float* uv    = (const float*)d_in[0];
  const float* w_in  = (const float*)d_in[1];
  const float* b_in  = (const float*)d_in[2];
  const float* w_hid = (const float*)d_in[3];
  const float* b_hid = (const float*)d_in[4];
  const float* w_out = (const float*)d_in[5];
  const float* b_out = (const float*)d_in[6];
  unsigned short* blob = (unsigned short*)d_ws;   // 1 MB bf16 permuted blob

  int whid_elems = in_sizes[3];                   // 524288
  convw_kernel<<<whid_elems / 256, 256, 0, stream>>>(w_hid, blob);

  int N = in_sizes[0] / 2;                        // 1048576 rows
  int grid = (N + MTILE - 1) / MTILE;             // 4096
  nld_kernel<<<grid, 256, 0, stream>>>(uv, w_in, b_in, b_hid, w_out, b_out,
                                       blob, (float*)d_out, N);
}